// Round 10
// baseline (116.932 us; speedup 1.0000x reference)
//
#include <hip/hip_runtime.h>

// Problem constants
#define BB   2
#define CIN  256
#define OC3  768
#define NG   4
#define GOC  64
#define C2   32
#define KK   49
#define PP   2304
#define HALF_P 1152

// Guarded Y2 layout (fp32, q band used only): rows -3..50 (54), cols -3..52
// at stride 56, 768 ch.
#define RS      56
#define BROWS   54
#define BSTRIDE (BROWS * RS * OC3)          // floats per batch
#define IOFF    ((3 * RS + 3) * OC3)

// K/V bands stored bf16 in separate guarded buffers (256 ch each)
#define BS2    (BROWS * RS * 256)           // ushorts per batch = 774,144
#define IOFF2  ((3 * RS + 3) * 256)

// Workspace layout (bytes)
#define Y2_BYTES  (BB * BROWS * RS * OC3 * 4)
#define XT_OFF    Y2_BYTES
#define WT_OFF    (XT_OFF + BB * PP * 512 * 2)
#define K2_OFF    (WT_OFF + 768 * 512 * 2)
#define V2_OFF    (K2_OFF + BB * BS2 * 2)

typedef __attribute__((ext_vector_type(8))) short bf16x8;
typedef __attribute__((ext_vector_type(4))) float f32x4;
typedef __attribute__((ext_vector_type(4))) unsigned short u16x4;

static __device__ __forceinline__ unsigned short f2bf_rne(float x) {
    unsigned int u = __float_as_uint(x);
    unsigned int r = u + 0x7FFFu + ((u >> 16) & 1u);
    return (unsigned short)(r >> 16);
}
static __device__ __forceinline__ float bf2f(unsigned short h) {
    return __uint_as_float(((unsigned int)h) << 16);
}

// 16B global -> LDS direct staging.
static __device__ __forceinline__ void gll16(const short* g, short* l) {
    __builtin_amdgcn_global_load_lds(
        (const __attribute__((address_space(1))) unsigned int*)g,
        (__attribute__((address_space(3))) unsigned int*)l,
        16, 0, 0);
}

// ---------------------------------------------------------------------------
// DPP-based exact xor-lane exchange (VALU pipe). Bit-identical semantics.
// ---------------------------------------------------------------------------
template <int C>
static __device__ __forceinline__ float dppf(float x) {
    return __int_as_float(__builtin_amdgcn_update_dpp(
        0, __float_as_int(x), C, 0xF, 0xF, true));
}
template <int D>
static __device__ __forceinline__ float xor_lane(float x) {
    if constexpr (D == 1)       return dppf<0xB1>(x);
    else if constexpr (D == 2)  return dppf<0x4E>(x);
    else if constexpr (D == 4)  return dppf<0x141>(dppf<0x4E>(dppf<0xB1>(x)));
    else if constexpr (D == 8)  return dppf<0x128>(x);
    else                        return __shfl_xor(x, D, 64);
}
template <int N> struct IC { static constexpr int value = N; };

// ---------------------------------------------------------------------------
// prep: converts only. blocks 0..767: convert_w ; 768..1055: convert_x. (R9)
// ---------------------------------------------------------------------------
__global__ __launch_bounds__(256) void prep(
    const float* __restrict__ W, short* __restrict__ Wt,
    const float* __restrict__ X, short* __restrict__ Xt)
{
    __shared__ float tile[64][65];
    const int bid = blockIdx.x;
    const int t   = threadIdx.x;

    if (bid < 768) {
        int tt = bid * 256 + t;                     // 0 .. 196607
        int o = tt >> 8, c = tt & 255;
        float v = W[tt];
        unsigned short hi = f2bf_rne(v);
        unsigned short lo = f2bf_rne(v - bf2f(hi));
        Wt[(size_t)o * 512 + c]       = (short)hi;
        Wt[(size_t)o * 512 + 256 + c] = (short)lo;
    } else {
        const int blk = bid - 768;                  // 0 .. 287
        const int p0  = (blk % 36) * 64;
        const int c0  = ((blk / 36) & 3) * 64;
        const int b   = blk / 144;

        const float* Xb = X + (size_t)b * CIN * PP;
        #pragma unroll
        for (int r = 0; r < 16; ++r) {
            int idx = r * 256 + t;
            int c = idx >> 6, p = idx & 63;
            tile[c][p] = Xb[(size_t)(c0 + c) * PP + p0 + p];
        }
        __syncthreads();
        short* Xo = Xt + (size_t)b * PP * 512;
        #pragma unroll
        for (int r = 0; r < 16; ++r) {
            int idx = r * 256 + t;
            int p = idx >> 6, c = idx & 63;
            float v = tile[c][p];
            unsigned short hi = f2bf_rne(v);
            unsigned short lo = f2bf_rne(v - bf2f(hi));
            size_t base = (size_t)(p0 + p) * 512 + c0 + c;
            Xo[base]       = (short)hi;
            Xo[base + 256] = (short)lo;
        }
    }
}

// ---------------------------------------------------------------------------
// Kernel 1: conv GEMM (2-phase dbuf gll16 pipe) + K2/V2 guard planes. (R9)
// ---------------------------------------------------------------------------
__global__ __launch_bounds__(256, 4) void conv_mfma(
    const short* __restrict__ Wt,   // (768, 512)
    const short* __restrict__ Xt,   // (B, 2304, 512)
    float* __restrict__ Y2,
    unsigned short* __restrict__ K2,
    unsigned short* __restrict__ V2)
{
    __shared__ short As[2][64 * 32];
    __shared__ short Bs[2][64 * 32];

    const int tid = threadIdx.x;
    const int bn  = blockIdx.x;       // p tile (36)
    const int bm  = blockIdx.y;       // o tile (12) or guard plane (12..16)
    const int b   = blockIdx.z;

    if (bm >= 12) {
        // ---- zero guard cells of K2/V2 ----
        const int idx = ((bm - 12) * 36 + bn) * 256 + tid;   // 0 .. 46079
        const int half = 23040;
        unsigned short* buf = ((idx < half) ? K2 : V2) + (size_t)b * BS2;
        const int id2  = (idx < half) ? idx : idx - half;    // 0 .. 23039
        const int cell = id2 >> 5;       // 0 .. 719
        const int chnk = id2 & 31;       // 32 x 16B per cell
        int r, ccol;
        if (cell < 336) {                // 6 full rows: 0,1,2,51,52,53
            int r6 = cell / 56; ccol = cell - r6 * 56;
            r = (r6 < 3) ? r6 : 48 + r6;
        } else {                         // rows 3..50, 8 guard cols
            int i2 = cell - 336; r = 3 + (i2 >> 3);
            int cg = i2 & 7; ccol = (cg < 3) ? cg : 48 + cg;
        }
        uint4* p = (uint4*)(buf + (size_t)(r * RS + ccol) * 256) + chnk;
        *p = make_uint4(0u, 0u, 0u, 0u);
        return;
    }

    const int om0 = bm * 64, pn0 = bn * 64;

    const int lane = tid & 63, w = tid >> 6;
    const int oq = (w & 1) * 32, pq = (w >> 1) * 32;
    const int ln15 = lane & 15, q = lane >> 4;

    const int R  = (w << 4) + (lane >> 2);
    const int sd = (lane & 3) ^ ((R >> 1) & 3);
    const short* gAq = Wt + (size_t)(om0 + R) * 512 + sd * 8;
    const short* gBq = Xt + (size_t)b * PP * 512 + (size_t)(pn0 + R) * 512 + sd * 8;

    const int swz = q ^ ((ln15 >> 1) & 3);

    f32x4 acc[2][2] = {};

    gll16(gAq + 0, &As[0][w * 512]);
    gll16(gBq + 0, &Bs[0][w * 512]);
    __syncthreads();

    for (int t = 0; t < 24; ++t) {
        const int cur = t & 1;

        bf16x8 af[2], bf[2];
        #pragma unroll
        for (int i = 0; i < 2; ++i) {
            af[i] = *(const bf16x8*)&As[cur][(oq + i * 16 + ln15) * 32 + swz * 8];
            bf[i] = *(const bf16x8*)&Bs[cur][(pq + i * 16 + ln15) * 32 + swz * 8];
        }

        if (t < 23) {
            const int k0 = 32 * (t + 1);
            const int wk = (k0 < 256) ? k0 : k0 - 256;   // W: hi, hi, lo
            const int xk = (k0 < 512) ? k0 : k0 - 512;   // X: hi, lo, hi
            gll16(gAq + wk, &As[cur ^ 1][w * 512]);
            gll16(gBq + xk, &Bs[cur ^ 1][w * 512]);
        }

        #pragma unroll
        for (int i = 0; i < 2; ++i)
            #pragma unroll
            for (int j = 0; j < 2; ++j)
                acc[i][j] = __builtin_amdgcn_mfma_f32_16x16x32_bf16(
                    af[i], bf[j], acc[i][j], 0, 0, 0);

        if (t < 23) __syncthreads();
    }

    // Epilogue. D[m=o][n=p]: lane = col p (ln15), rows o = q*4..+3 contiguous
    if (bm < 4) {
        float* Yb = Y2 + (size_t)b * BSTRIDE + IOFF;
        #pragma unroll
        for (int i = 0; i < 2; ++i) {
            #pragma unroll
            for (int j = 0; j < 2; ++j) {
                int o = om0 + oq + i * 16 + q * 4;
                int p = pn0 + pq + j * 16 + ln15;
                int h = p / 48, ww = p - h * 48;
                *(f32x4*)&Yb[(size_t)(h * RS + ww) * OC3 + o] = acc[i][j];
            }
        }
    } else {
        unsigned short* dst = ((bm < 8) ? K2 : V2) + (size_t)b * BS2 + IOFF2;
        const int obase = om0 - ((bm < 8) ? 256 : 512);
        #pragma unroll
        for (int i = 0; i < 2; ++i) {
            #pragma unroll
            for (int j = 0; j < 2; ++j) {
                int o = obase + oq + i * 16 + q * 4;
                int p = pn0 + pq + j * 16 + ln15;
                int h = p / 48, ww = p - h * 48;
                u16x4 pk;
                #pragma unroll
                for (int cc = 0; cc < 4; ++cc) pk[cc] = f2bf_rne(acc[i][j][cc]);
                *(u16x4*)&dst[(size_t)(h * RS + ww) * 256 + o] = pk;
            }
        }
    }
}

// ---------------------------------------------------------------------------
// Kernel 2: attention. r15: SINGLE runtime-use_h tree (was two template
// instantiations). ra/rc become one v_cndmask between constant-folded
// registers -> ~1000 fewer straight-line instructions (~38% of code),
// testing the instruction-fetch-bound hypothesis. Values selected and op
// order identical -> bit-identical output vs R9.
// ---------------------------------------------------------------------------
__global__ __launch_bounds__(256, 6) void attn_kernel(
    const float* __restrict__ Y2,
    const unsigned short* __restrict__ K2,
    const unsigned short* __restrict__ V2,
    const float* __restrict__ rpe_h,  // (4,1,7,1,32)
    const float* __restrict__ rpe_w,  // (4,1,1,7,32)
    float* __restrict__ out)          // (B, 256, 48, 48)
{
    __shared__ float xpose[4][65];

    const int tid  = threadIdx.x;
    const int lane = tid & 63;
    const int w    = tid >> 6;
    const int bx     = blockIdx.x;
    const int wblock = (bx & 7) * 576 + (bx >> 3);
    const int wid    = wblock * 4 + w;
    const int pq   = wid % PP;
    const int g    = (wid / PP) & (NG - 1);
    const int b    = wid / (PP * NG);
    const int ph   = pq / 48;
    const int pw   = pq - ph * 48;

    const float* Yb = Y2 + (size_t)b * BSTRIDE + IOFF;

    const float qv = Yb[(size_t)(ph * RS + pw) * OC3 + g * GOC + lane];

    const int t   = (pq >= HALF_P) ? 1 : 0;
    const int qpr = pq - t * HALF_P;
    const int p0  = 2 * qpr;
    const int ph0 = p0 / 48;
    const int pw0 = p0 - ph0 * 48;
    const int g2  = 2 * g + t;
    const bool use_h = (g2 < NG);
    const int  kch2  = use_h ? (g2 * GOC) : ((g2 - NG) * GOC + C2);
    const float* rb  = use_h ? (rpe_h + g2 * 7 * C2) : (rpe_w + (g2 - NG) * 7 * C2);

    const int  c  = lane & 31;
    const bool hi = (lane >= 32);

    const float R0 = rb[0 * C2 + c], R1 = rb[1 * C2 + c], R2 = rb[2 * C2 + c],
                R3 = rb[3 * C2 + c], R4 = rb[4 * C2 + c], R5 = rb[5 * C2 + c],
                R6 = rb[6 * C2 + c];

    const unsigned short* kb = K2 + (size_t)b * BS2 + IOFF2
                             + (size_t)(ph0 * RS + pw0) * 256 + kch2 + c;

    auto rget = [&](int idx) -> float {
        return idx == 0 ? R0 : idx == 1 ? R1 : idx == 2 ? R2 :
               idx == 3 ? R3 : idx == 4 ? R4 : idx == 5 ? R5 : R6;
    };

    // r15: single tree, use_h resolved at runtime (wave-uniform; one
    // v_cndmask per chunkprod between constant-folded rget values).
    auto tree = [&]() -> float {
        auto chunkprod = [&](int l) -> float {
            int m0 = 2 * l,     h10 = (m0 >= KK), k0 = m0 - KK * h10;
            int m1 = 2 * l + 1, h11 = (m1 >= KK), k1 = m1 - KK * h11;
            int i0 = k0 / 7, j0 = k0 % 7, i1 = k1 / 7, j1 = k1 % 7;
            int d0 = ((i0 - 3) * RS + (h10 + j0 - 3)) * 256;
            int d1 = ((i1 - 3) * RS + (h11 + j1 - 3)) * 256;
            float kv = bf2f(kb[hi ? d1 : d0]);
            float ra = use_h ? rget(i0) : rget(j0);
            float rc = use_h ? rget(i1) : rget(j1);
            kv += hi ? rc : ra;
            return qv * kv;
        };
        auto val = [&](int jj) -> float {
            if (2 * jj >= KK) return 0.f;
            float pa = chunkprod(2 * jj);
            float pb = (2 * jj + 1 < KK) ? chunkprod(2 * jj + 1) : 0.f;
            float u  = (lane & 1) ? pb : pa;
            float ww = (lane & 1) ? pa : pb;
            return u + xor_lane<1>(ww);
        };
        auto comb = [&](auto dc, float x, float y) -> float {
            constexpr int d = decltype(dc)::value;
            float u  = (lane & d) ? y : x;
            float ww = (lane & d) ? x : y;
            return u + xor_lane<d>(ww);
        };
        float acc32[2];
        #pragma unroll
        for (int a = 0; a < 2; ++a) {
            float acc16[2];
            #pragma unroll
            for (int bq = 0; bq < 2; ++bq) {
                float acc8[2];
                #pragma unroll
                for (int cq2 = 0; cq2 < 2; ++cq2) {
                    float acc4t[2];
                    #pragma unroll
                    for (int dq = 0; dq < 2; ++dq) {
                        float acc2[2];
                        #pragma unroll
                        for (int eq = 0; eq < 2; ++eq)
                            acc2[eq] = val(a * 16 + bq * 8 + cq2 * 4 + dq * 2 + eq);
                        acc4t[dq] = comb(IC<2>{}, acc2[0], acc2[1]);
                    }
                    acc8[cq2] = comb(IC<4>{}, acc4t[0], acc4t[1]);
                }
                acc16[bq] = comb(IC<8>{}, acc8[0], acc8[1]);
            }
            acc32[a] = comb(IC<16>{}, acc16[0], acc16[1]);
        }
        return comb(IC<32>{}, acc32[0], acc32[1]);
    };

    const float logit = tree();

    float mx = logit;
    mx = fmaxf(mx, xor_lane<1>(mx));
    mx = fmaxf(mx, xor_lane<2>(mx));
    mx = fmaxf(mx, xor_lane<4>(mx));
    mx = fmaxf(mx, xor_lane<8>(mx));
    mx = fmaxf(mx, xor_lane<16>(mx));
    mx = fmaxf(mx, xor_lane<32>(mx));
    float e = (lane < KK) ? __expf(logit - mx) : 0.f;
    float ssum = e;
    ssum += xor_lane<1>(ssum);
    ssum += xor_lane<2>(ssum);
    ssum += xor_lane<4>(ssum);
    ssum += xor_lane<8>(ssum);
    ssum += xor_lane<16>(ssum);
    ssum += xor_lane<32>(ssum);
    const float att = e / ssum;

    float acc = 0.f;
    const unsigned short* vb = V2 + (size_t)b * BS2 + IOFF2
                             + (size_t)(ph * RS + pw) * 256 + g * GOC + lane;
    #pragma unroll
    for (int k = 0; k < KK; ++k) {
        int i = k / 7, j = k % 7;
        int doff = ((i - 3) * RS + (j - 3)) * 256;
        float ak = __uint_as_float(
            __builtin_amdgcn_readlane(__float_as_uint(att), k));
        acc = fmaf(ak, bf2f(vb[doff]), acc);
    }

    xpose[w][lane] = acc;
    __syncthreads();
    const int wid0 = wblock * 4;
    const int pq0  = wid0 % PP;
    const int g0   = (wid0 / PP) & (NG - 1);
    const int b0   = wid0 / (PP * NG);
    const int ch   = tid >> 2;
    const int w2   = tid & 3;
    out[((size_t)b0 * 256 + g0 * GOC + ch) * PP + pq0 + w2] = xpose[w2][ch];
}

// ---------------------------------------------------------------------------
extern "C" void kernel_launch(void* const* d_in, const int* in_sizes, int n_in,
                              void* d_out, int out_size, void* d_ws, size_t ws_size,
                              hipStream_t stream)
{
    const float* x  = (const float*)d_in[0];
    const float* w  = (const float*)d_in[1];
    const float* rh = (const float*)d_in[2];
    const float* rw = (const float*)d_in[3];

    float* Y2 = (float*)d_ws;
    short* Xt = (short*)((char*)d_ws + XT_OFF);
    short* Wt = (short*)((char*)d_ws + WT_OFF);
    unsigned short* K2 = (unsigned short*)((char*)d_ws + K2_OFF);
    unsigned short* V2 = (unsigned short*)((char*)d_ws + V2_OFF);

    prep<<<1056, 256, 0, stream>>>(w, Wt, x, Xt);
    // bm 0..11: GEMM o-tiles; bm 12..16: K2/V2 guard zeroing
    conv_mfma<<<dim3(36, 17, BB), 256, 0, stream>>>(Wt, Xt, Y2, K2, V2);
    attn_kernel<<<(BB * NG * PP) / 4, 256, 0, stream>>>(Y2, K2, V2, rh, rw, (float*)d_out);
}

// Round 11
// 103.764 us; speedup vs baseline: 1.1269x; 1.1269x over previous
//
#include <hip/hip_runtime.h>

// Problem constants
#define BB   2
#define CIN  256
#define OC3  768
#define NG   4
#define GOC  64
#define C2   32
#define KK   49
#define PP   2304
#define HALF_P 1152

// Guarded Y2 layout (fp32, q band used only): rows -3..50 (54), cols -3..52
// at stride 56, 768 ch.
#define RS      56
#define BROWS   54
#define BSTRIDE (BROWS * RS * OC3)          // floats per batch
#define IOFF    ((3 * RS + 3) * OC3)

// K/V bands stored bf16 in separate guarded buffers (256 ch each)
#define BS2    (BROWS * RS * 256)           // ushorts per batch = 774,144
#define IOFF2  ((3 * RS + 3) * 256)

// Workspace layout (bytes)
#define Y2_BYTES  (BB * BROWS * RS * OC3 * 4)
#define XT_OFF    Y2_BYTES
#define WT_OFF    (XT_OFF + BB * PP * 512 * 2)
#define K2_OFF    (WT_OFF + 768 * 512 * 2)
#define V2_OFF    (K2_OFF + BB * BS2 * 2)

typedef __attribute__((ext_vector_type(8))) short bf16x8;
typedef __attribute__((ext_vector_type(4))) float f32x4;
typedef __attribute__((ext_vector_type(4))) unsigned short u16x4;

static __device__ __forceinline__ unsigned short f2bf_rne(float x) {
    unsigned int u = __float_as_uint(x);
    unsigned int r = u + 0x7FFFu + ((u >> 16) & 1u);
    return (unsigned short)(r >> 16);
}
static __device__ __forceinline__ float bf2f(unsigned short h) {
    return __uint_as_float(((unsigned int)h) << 16);
}

// 16B global -> LDS direct staging.
static __device__ __forceinline__ void gll16(const short* g, short* l) {
    __builtin_amdgcn_global_load_lds(
        (const __attribute__((address_space(1))) unsigned int*)g,
        (__attribute__((address_space(3))) unsigned int*)l,
        16, 0, 0);
}

// ---------------------------------------------------------------------------
// DPP-based exact xor-lane exchange (VALU pipe). Bit-identical semantics.
// ---------------------------------------------------------------------------
template <int C>
static __device__ __forceinline__ float dppf(float x) {
    return __int_as_float(__builtin_amdgcn_update_dpp(
        0, __float_as_int(x), C, 0xF, 0xF, true));
}
template <int D>
static __device__ __forceinline__ float xor_lane(float x) {
    if constexpr (D == 1)       return dppf<0xB1>(x);
    else if constexpr (D == 2)  return dppf<0x4E>(x);
    else if constexpr (D == 4)  return dppf<0x141>(dppf<0x4E>(dppf<0xB1>(x)));
    else if constexpr (D == 8)  return dppf<0x128>(x);
    else                        return __shfl_xor(x, D, 64);
}
template <int N> struct IC { static constexpr int value = N; };

// ---------------------------------------------------------------------------
// prep: converts only. blocks 0..767: convert_w ; 768..1055: convert_x. (R9)
// ---------------------------------------------------------------------------
__global__ __launch_bounds__(256) void prep(
    const float* __restrict__ W, short* __restrict__ Wt,
    const float* __restrict__ X, short* __restrict__ Xt)
{
    __shared__ float tile[64][65];
    const int bid = blockIdx.x;
    const int t   = threadIdx.x;

    if (bid < 768) {
        int tt = bid * 256 + t;                     // 0 .. 196607
        int o = tt >> 8, c = tt & 255;
        float v = W[tt];
        unsigned short hi = f2bf_rne(v);
        unsigned short lo = f2bf_rne(v - bf2f(hi));
        Wt[(size_t)o * 512 + c]       = (short)hi;
        Wt[(size_t)o * 512 + 256 + c] = (short)lo;
    } else {
        const int blk = bid - 768;                  // 0 .. 287
        const int p0  = (blk % 36) * 64;
        const int c0  = ((blk / 36) & 3) * 64;
        const int b   = blk / 144;

        const float* Xb = X + (size_t)b * CIN * PP;
        #pragma unroll
        for (int r = 0; r < 16; ++r) {
            int idx = r * 256 + t;
            int c = idx >> 6, p = idx & 63;
            tile[c][p] = Xb[(size_t)(c0 + c) * PP + p0 + p];
        }
        __syncthreads();
        short* Xo = Xt + (size_t)b * PP * 512;
        #pragma unroll
        for (int r = 0; r < 16; ++r) {
            int idx = r * 256 + t;
            int p = idx >> 6, c = idx & 63;
            float v = tile[c][p];
            unsigned short hi = f2bf_rne(v);
            unsigned short lo = f2bf_rne(v - bf2f(hi));
            size_t base = (size_t)(p0 + p) * 512 + c0 + c;
            Xo[base]       = (short)hi;
            Xo[base + 256] = (short)lo;
        }
    }
}

// ---------------------------------------------------------------------------
// Kernel 1: conv GEMM (2-phase dbuf gll16 pipe) + K2/V2 guard planes. (R9)
// ---------------------------------------------------------------------------
__global__ __launch_bounds__(256, 4) void conv_mfma(
    const short* __restrict__ Wt,   // (768, 512)
    const short* __restrict__ Xt,   // (B, 2304, 512)
    float* __restrict__ Y2,
    unsigned short* __restrict__ K2,
    unsigned short* __restrict__ V2)
{
    __shared__ short As[2][64 * 32];
    __shared__ short Bs[2][64 * 32];

    const int tid = threadIdx.x;
    const int bn  = blockIdx.x;       // p tile (36)
    const int bm  = blockIdx.y;       // o tile (12) or guard plane (12..16)
    const int b   = blockIdx.z;

    if (bm >= 12) {
        // ---- zero guard cells of K2/V2 ----
        const int idx = ((bm - 12) * 36 + bn) * 256 + tid;   // 0 .. 46079
        const int half = 23040;
        unsigned short* buf = ((idx < half) ? K2 : V2) + (size_t)b * BS2;
        const int id2  = (idx < half) ? idx : idx - half;    // 0 .. 23039
        const int cell = id2 >> 5;       // 0 .. 719
        const int chnk = id2 & 31;       // 32 x 16B per cell
        int r, ccol;
        if (cell < 336) {                // 6 full rows: 0,1,2,51,52,53
            int r6 = cell / 56; ccol = cell - r6 * 56;
            r = (r6 < 3) ? r6 : 48 + r6;
        } else {                         // rows 3..50, 8 guard cols
            int i2 = cell - 336; r = 3 + (i2 >> 3);
            int cg = i2 & 7; ccol = (cg < 3) ? cg : 48 + cg;
        }
        uint4* p = (uint4*)(buf + (size_t)(r * RS + ccol) * 256) + chnk;
        *p = make_uint4(0u, 0u, 0u, 0u);
        return;
    }

    const int om0 = bm * 64, pn0 = bn * 64;

    const int lane = tid & 63, w = tid >> 6;
    const int oq = (w & 1) * 32, pq = (w >> 1) * 32;
    const int ln15 = lane & 15, q = lane >> 4;

    const int R  = (w << 4) + (lane >> 2);
    const int sd = (lane & 3) ^ ((R >> 1) & 3);
    const short* gAq = Wt + (size_t)(om0 + R) * 512 + sd * 8;
    const short* gBq = Xt + (size_t)b * PP * 512 + (size_t)(pn0 + R) * 512 + sd * 8;

    const int swz = q ^ ((ln15 >> 1) & 3);

    f32x4 acc[2][2] = {};

    gll16(gAq + 0, &As[0][w * 512]);
    gll16(gBq + 0, &Bs[0][w * 512]);
    __syncthreads();

    for (int t = 0; t < 24; ++t) {
        const int cur = t & 1;

        bf16x8 af[2], bf[2];
        #pragma unroll
        for (int i = 0; i < 2; ++i) {
            af[i] = *(const bf16x8*)&As[cur][(oq + i * 16 + ln15) * 32 + swz * 8];
            bf[i] = *(const bf16x8*)&Bs[cur][(pq + i * 16 + ln15) * 32 + swz * 8];
        }

        if (t < 23) {
            const int k0 = 32 * (t + 1);
            const int wk = (k0 < 256) ? k0 : k0 - 256;   // W: hi, hi, lo
            const int xk = (k0 < 512) ? k0 : k0 - 512;   // X: hi, lo, hi
            gll16(gAq + wk, &As[cur ^ 1][w * 512]);
            gll16(gBq + xk, &Bs[cur ^ 1][w * 512]);
        }

        #pragma unroll
        for (int i = 0; i < 2; ++i)
            #pragma unroll
            for (int j = 0; j < 2; ++j)
                acc[i][j] = __builtin_amdgcn_mfma_f32_16x16x32_bf16(
                    af[i], bf[j], acc[i][j], 0, 0, 0);

        if (t < 23) __syncthreads();
    }

    // Epilogue. D[m=o][n=p]: lane = col p (ln15), rows o = q*4..+3 contiguous
    if (bm < 4) {
        float* Yb = Y2 + (size_t)b * BSTRIDE + IOFF;
        #pragma unroll
        for (int i = 0; i < 2; ++i) {
            #pragma unroll
            for (int j = 0; j < 2; ++j) {
                int o = om0 + oq + i * 16 + q * 4;
                int p = pn0 + pq + j * 16 + ln15;
                int h = p / 48, ww = p - h * 48;
                *(f32x4*)&Yb[(size_t)(h * RS + ww) * OC3 + o] = acc[i][j];
            }
        }
    } else {
        unsigned short* dst = ((bm < 8) ? K2 : V2) + (size_t)b * BS2 + IOFF2;
        const int obase = om0 - ((bm < 8) ? 256 : 512);
        #pragma unroll
        for (int i = 0; i < 2; ++i) {
            #pragma unroll
            for (int j = 0; j < 2; ++j) {
                int o = obase + oq + i * 16 + q * 4;
                int p = pn0 + pq + j * 16 + ln15;
                int h = p / 48, ww = p - h * 48;
                u16x4 pk;
                #pragma unroll
                for (int cc = 0; cc < 4; ++cc) pk[cc] = f2bf_rne(acc[i][j][cc]);
                *(u16x4*)&dst[(size_t)(h * RS + ww) * 256 + o] = pk;
            }
        }
    }
}

// ---------------------------------------------------------------------------
// Kernel 2: attention (R9-exact: two-template tree, streaming reduction,
// DPP exchanges, scalar taps, bf16 K/V). R10's runtime-use_h variant
// regressed (+13us: cndmask live-range pressure under the (256,6) VGPR cap)
// and is reverted.
// ---------------------------------------------------------------------------
struct TagH { static constexpr bool value = true;  };
struct TagW { static constexpr bool value = false; };

__global__ __launch_bounds__(256, 6) void attn_kernel(
    const float* __restrict__ Y2,
    const unsigned short* __restrict__ K2,
    const unsigned short* __restrict__ V2,
    const float* __restrict__ rpe_h,  // (4,1,7,1,32)
    const float* __restrict__ rpe_w,  // (4,1,1,7,32)
    float* __restrict__ out)          // (B, 256, 48, 48)
{
    __shared__ float xpose[4][65];

    const int tid  = threadIdx.x;
    const int lane = tid & 63;
    const int w    = tid >> 6;
    const int bx     = blockIdx.x;
    const int wblock = (bx & 7) * 576 + (bx >> 3);
    const int wid    = wblock * 4 + w;
    const int pq   = wid % PP;
    const int g    = (wid / PP) & (NG - 1);
    const int b    = wid / (PP * NG);
    const int ph   = pq / 48;
    const int pw   = pq - ph * 48;

    const float* Yb = Y2 + (size_t)b * BSTRIDE + IOFF;

    const float qv = Yb[(size_t)(ph * RS + pw) * OC3 + g * GOC + lane];

    const int t   = (pq >= HALF_P) ? 1 : 0;
    const int qpr = pq - t * HALF_P;
    const int p0  = 2 * qpr;
    const int ph0 = p0 / 48;
    const int pw0 = p0 - ph0 * 48;
    const int g2  = 2 * g + t;
    const bool use_h = (g2 < NG);
    const int  kch2  = use_h ? (g2 * GOC) : ((g2 - NG) * GOC + C2);
    const float* rb  = use_h ? (rpe_h + g2 * 7 * C2) : (rpe_w + (g2 - NG) * 7 * C2);

    const int  c  = lane & 31;
    const bool hi = (lane >= 32);

    const float R0 = rb[0 * C2 + c], R1 = rb[1 * C2 + c], R2 = rb[2 * C2 + c],
                R3 = rb[3 * C2 + c], R4 = rb[4 * C2 + c], R5 = rb[5 * C2 + c],
                R6 = rb[6 * C2 + c];

    const unsigned short* kb = K2 + (size_t)b * BS2 + IOFF2
                             + (size_t)(ph0 * RS + pw0) * 256 + kch2 + c;

    auto rget = [&](int idx) -> float {
        return idx == 0 ? R0 : idx == 1 ? R1 : idx == 2 ? R2 :
               idx == 3 ? R3 : idx == 4 ? R4 : idx == 5 ? R5 : R6;
    };

    auto tree = [&](auto tag) -> float {
        constexpr bool UH = decltype(tag)::value;
        auto chunkprod = [&](int l) -> float {
            int m0 = 2 * l,     h10 = (m0 >= KK), k0 = m0 - KK * h10;
            int m1 = 2 * l + 1, h11 = (m1 >= KK), k1 = m1 - KK * h11;
            int i0 = k0 / 7, j0 = k0 % 7, i1 = k1 / 7, j1 = k1 % 7;
            int d0 = ((i0 - 3) * RS + (h10 + j0 - 3)) * 256;
            int d1 = ((i1 - 3) * RS + (h11 + j1 - 3)) * 256;
            float kv = bf2f(kb[hi ? d1 : d0]);
            float ra = UH ? rget(i0) : rget(j0);
            float rc = UH ? rget(i1) : rget(j1);
            kv += hi ? rc : ra;
            return qv * kv;
        };
        auto val = [&](int jj) -> float {
            if (2 * jj >= KK) return 0.f;
            float pa = chunkprod(2 * jj);
            float pb = (2 * jj + 1 < KK) ? chunkprod(2 * jj + 1) : 0.f;
            float u  = (lane & 1) ? pb : pa;
            float ww = (lane & 1) ? pa : pb;
            return u + xor_lane<1>(ww);
        };
        auto comb = [&](auto dc, float x, float y) -> float {
            constexpr int d = decltype(dc)::value;
            float u  = (lane & d) ? y : x;
            float ww = (lane & d) ? x : y;
            return u + xor_lane<d>(ww);
        };
        float acc32[2];
        #pragma unroll
        for (int a = 0; a < 2; ++a) {
            float acc16[2];
            #pragma unroll
            for (int bq = 0; bq < 2; ++bq) {
                float acc8[2];
                #pragma unroll
                for (int cq2 = 0; cq2 < 2; ++cq2) {
                    float acc4t[2];
                    #pragma unroll
                    for (int dq = 0; dq < 2; ++dq) {
                        float acc2[2];
                        #pragma unroll
                        for (int eq = 0; eq < 2; ++eq)
                            acc2[eq] = val(a * 16 + bq * 8 + cq2 * 4 + dq * 2 + eq);
                        acc4t[dq] = comb(IC<2>{}, acc2[0], acc2[1]);
                    }
                    acc8[cq2] = comb(IC<4>{}, acc4t[0], acc4t[1]);
                }
                acc16[bq] = comb(IC<8>{}, acc8[0], acc8[1]);
            }
            acc32[a] = comb(IC<16>{}, acc16[0], acc16[1]);
        }
        return comb(IC<32>{}, acc32[0], acc32[1]);
    };

    const float logit = use_h ? tree(TagH{}) : tree(TagW{});

    float mx = logit;
    mx = fmaxf(mx, xor_lane<1>(mx));
    mx = fmaxf(mx, xor_lane<2>(mx));
    mx = fmaxf(mx, xor_lane<4>(mx));
    mx = fmaxf(mx, xor_lane<8>(mx));
    mx = fmaxf(mx, xor_lane<16>(mx));
    mx = fmaxf(mx, xor_lane<32>(mx));
    float e = (lane < KK) ? __expf(logit - mx) : 0.f;
    float ssum = e;
    ssum += xor_lane<1>(ssum);
    ssum += xor_lane<2>(ssum);
    ssum += xor_lane<4>(ssum);
    ssum += xor_lane<8>(ssum);
    ssum += xor_lane<16>(ssum);
    ssum += xor_lane<32>(ssum);
    const float att = e / ssum;

    float acc = 0.f;
    const unsigned short* vb = V2 + (size_t)b * BS2 + IOFF2
                             + (size_t)(ph * RS + pw) * 256 + g * GOC + lane;
    #pragma unroll
    for (int k = 0; k < KK; ++k) {
        int i = k / 7, j = k % 7;
        int doff = ((i - 3) * RS + (j - 3)) * 256;
        float ak = __uint_as_float(
            __builtin_amdgcn_readlane(__float_as_uint(att), k));
        acc = fmaf(ak, bf2f(vb[doff]), acc);
    }

    xpose[w][lane] = acc;
    __syncthreads();
    const int wid0 = wblock * 4;
    const int pq0  = wid0 % PP;
    const int g0   = (wid0 / PP) & (NG - 1);
    const int b0   = wid0 / (PP * NG);
    const int ch   = tid >> 2;
    const int w2   = tid & 3;
    out[((size_t)b0 * 256 + g0 * GOC + ch) * PP + pq0 + w2] = xpose[w2][ch];
}

// ---------------------------------------------------------------------------
extern "C" void kernel_launch(void* const* d_in, const int* in_sizes, int n_in,
                              void* d_out, int out_size, void* d_ws, size_t ws_size,
                              hipStream_t stream)
{
    const float* x  = (const float*)d_in[0];
    const float* w  = (const float*)d_in[1];
    const float* rh = (const float*)d_in[2];
    const float* rw = (const float*)d_in[3];

    float* Y2 = (float*)d_ws;
    short* Xt = (short*)((char*)d_ws + XT_OFF);
    short* Wt = (short*)((char*)d_ws + WT_OFF);
    unsigned short* K2 = (unsigned short*)((char*)d_ws + K2_OFF);
    unsigned short* V2 = (unsigned short*)((char*)d_ws + V2_OFF);

    prep<<<1056, 256, 0, stream>>>(w, Wt, x, Xt);
    // bm 0..11: GEMM o-tiles; bm 12..16: K2/V2 guard zeroing
    conv_mfma<<<dim3(36, 17, BB), 256, 0, stream>>>(Wt, Xt, Y2, K2, V2);
    attn_kernel<<<(BB * NG * PP) / 4, 256, 0, stream>>>(Y2, K2, V2, rh, rw, (float*)d_out);
}